// Round 1
// baseline (1714.938 us; speedup 1.0000x reference)
//
#include <hip/hip_runtime.h>
#include <math.h>

#define NN 32
#define LL 8192
#define CI1 64
#define CO 128
#define KK 5
#define TT 10
#define EE 5
#define LD (LL/2)

__device__ __forceinline__ float mishf(float x) {
    float sp = (x > 20.f) ? x : log1pf(expf(x));
    return x * tanhf(sp);
}

// ---------------- gates: softmax over experts ----------------
__global__ void gates_kernel(const float* __restrict__ t,
                             const float* __restrict__ gw1, const float* __restrict__ gb1,
                             const float* __restrict__ gw2, const float* __restrict__ gb2,
                             float* __restrict__ g1, float* __restrict__ g2) {
    int idx = blockIdx.x * blockDim.x + threadIdx.x;
    if (idx >= 2 * NN * CO) return;
    int layer = idx / (NN * CO);
    int r = idx % (NN * CO);
    int n = r / CO, co = r % CO;
    const float* gw = layer ? gw2 : gw1;
    const float* gb = layer ? gb2 : gb1;
    float* g = layer ? g2 : g1;
    float tv[TT];
    #pragma unroll
    for (int i = 0; i < TT; i++) tv[i] = t[n * TT + i];
    float lg[EE];
    float m = -1e30f;
    #pragma unroll
    for (int e = 0; e < EE; e++) {
        int row = e * CO + co;
        float s = gb[row];
        #pragma unroll
        for (int i = 0; i < TT; i++) s = fmaf(tv[i], gw[row * TT + i], s);
        lg[e] = s;
        m = fmaxf(m, s);
    }
    float den = 0.f;
    #pragma unroll
    for (int e = 0; e < EE; e++) { lg[e] = expf(lg[e] - m); den += lg[e]; }
    float inv = 1.f / den;
    #pragma unroll
    for (int e = 0; e < EE; e++) g[(n * EE + e) * CO + co] = lg[e] * inv;
}

// ------------- per-sample mixed kernels w[n][ci][k][co] -------------
template <int CI>
__global__ void weights_kernel(const float* __restrict__ g,
                               const float* __restrict__ k5, const float* __restrict__ k3,
                               const float* __restrict__ k1, const float* __restrict__ a3,
                               const float* __restrict__ a5, float* __restrict__ w) {
    int idx = blockIdx.x * blockDim.x + threadIdx.x;
    if (idx >= NN * CI * CO) return;
    int co = idx % CO;
    int ci = (idx / CO) % CI;
    int n = idx / (CO * CI);
    float gg[EE];
    #pragma unroll
    for (int e = 0; e < EE; e++) gg[e] = g[(n * EE + e) * CO + co];
    int b = co * CI + ci;
    float wv[KK];
    float aa3 = a3[b] * (1.f / 3.f) * gg[3];
    float aa5 = a5[b] * (1.f / 5.f) * gg[4];
    #pragma unroll
    for (int k = 0; k < KK; k++) wv[k] = gg[0] * k5[b * KK + k] + aa5;
    #pragma unroll
    for (int k = 0; k < 3; k++) wv[k + 2] += fmaf(gg[1], k3[b * 3 + k], aa3) - 0.f;
    wv[4] += gg[2] * k1[b];
    #pragma unroll
    for (int k = 0; k < KK; k++) w[((size_t)(n * CI + ci) * KK + k) * CO + co] = wv[k];
}

// ------------- transpose (N,L,C) -> (N,C,L) -------------
template <int CCH>
__global__ void transpose_in(const float* __restrict__ src, float* __restrict__ dst) {
    __shared__ float tile[64][65];
    int n = blockIdx.z, c0 = blockIdx.y * 64, l0 = blockIdx.x * 64;
    int tid = threadIdx.x;
    int ci = tid % 64, g4 = tid / 64;
    #pragma unroll
    for (int i = 0; i < 16; i++) {
        int li = g4 * 16 + i;
        tile[li][ci] = src[((size_t)n * LL + l0 + li) * CCH + c0 + ci];
    }
    __syncthreads();
    int li = tid % 64, cg = tid / 64;
    #pragma unroll
    for (int i = 0; i < 16; i++) {
        int ci2 = cg * 16 + i;
        dst[((size_t)n * CCH + c0 + ci2) * LL + l0 + li] = tile[li][ci2];
    }
}

// ------------- transpose (N,CO,L) -> (N,L,CO) -------------
__global__ void transpose_out(const float* __restrict__ src, float* __restrict__ dst) {
    __shared__ float tile[64][65];
    int n = blockIdx.z, c0 = blockIdx.y * 64, l0 = blockIdx.x * 64;
    int tid = threadIdx.x;
    int li = tid % 64, cg = tid / 64;
    #pragma unroll
    for (int i = 0; i < 16; i++) {
        int ci = cg * 16 + i;
        tile[ci][li] = src[((size_t)n * CO + c0 + ci) * LL + l0 + li];
    }
    __syncthreads();
    int ci2 = tid % 64, lg = tid / 64;
    #pragma unroll
    for (int i = 0; i < 16; i++) {
        int li2 = lg * 16 + i;
        dst[((size_t)n * LL + l0 + li2) * CO + c0 + ci2] = tile[ci2][li2];
    }
}

// ------------- causal K=5 grouped-by-sample conv, tiled -------------
// input xT (N,CI,L) channel-major, weights w (N,CI,K,CO), output y (N,CO,L)
template <int CI>
__global__ __launch_bounds__(256)
void conv_mode(const float* __restrict__ xT, const float* __restrict__ w,
               float* __restrict__ y) {
    __shared__ float x_lds[16][132];
    __shared__ float w_lds[16][5][64];
    int n = blockIdx.z;
    int co0 = blockIdx.y * 64;
    int l0 = blockIdx.x * 128;
    int tid = threadIdx.x;
    int tl = tid & 31, tc = tid >> 5;
    float acc[8][4];
    #pragma unroll
    for (int c = 0; c < 8; c++)
        #pragma unroll
        for (int j = 0; j < 4; j++) acc[c][j] = 0.f;
    const float* xbase = xT + (size_t)n * CI * LL;
    const float* wbase = w + (size_t)n * CI * KK * CO;
    for (int ci0 = 0; ci0 < CI; ci0 += 16) {
        for (int idx = tid; idx < 16 * 132; idx += 256) {
            int ci = idx / 132, j = idx % 132;
            int ll = l0 - 4 + j;
            x_lds[ci][j] = (ll >= 0) ? xbase[(size_t)(ci0 + ci) * LL + ll] : 0.f;
        }
        for (int idx = tid; idx < 16 * 5 * 64; idx += 256) {
            int co = idx & 63;
            int rest = idx >> 6;
            int k = rest % 5, ci = rest / 5;
            w_lds[ci][k][co] = wbase[((size_t)(ci0 + ci) * KK + k) * CO + co0 + co];
        }
        __syncthreads();
        #pragma unroll 4
        for (int ci = 0; ci < 16; ci++) {
            float xw[8];
            *(float4*)&xw[0] = *(const float4*)&x_lds[ci][tl * 4];
            *(float4*)&xw[4] = *(const float4*)&x_lds[ci][tl * 4 + 4];
            #pragma unroll
            for (int k = 0; k < 5; k++) {
                float wv[8];
                *(float4*)&wv[0] = *(const float4*)&w_lds[ci][k][tc * 8];
                *(float4*)&wv[4] = *(const float4*)&w_lds[ci][k][tc * 8 + 4];
                #pragma unroll
                for (int c = 0; c < 8; c++)
                    #pragma unroll
                    for (int j = 0; j < 4; j++)
                        acc[c][j] = fmaf(wv[c], xw[j + k], acc[c][j]);
            }
        }
        __syncthreads();
    }
    float* yb = y + ((size_t)n * CO + co0 + tc * 8) * LL + l0 + tl * 4;
    #pragma unroll
    for (int c = 0; c < 8; c++) {
        *(float4*)&yb[(size_t)c * LL] = *(float4*)&acc[c][0];
    }
}

// ------------- per-(n,co) row mean/rstd -------------
__global__ void rowstat(const float* __restrict__ y, float* __restrict__ stats) {
    int row = blockIdx.x;
    const float4* p = (const float4*)(y + (size_t)row * LL);
    int tid = threadIdx.x;
    float s = 0.f, q = 0.f;
    for (int i = tid; i < LL / 4; i += 256) {
        float4 v = p[i];
        s += v.x + v.y + v.z + v.w;
        q += v.x * v.x + v.y * v.y + v.z * v.z + v.w * v.w;
    }
    #pragma unroll
    for (int off = 32; off > 0; off >>= 1) {
        s += __shfl_down(s, off, 64);
        q += __shfl_down(q, off, 64);
    }
    __shared__ float ls[4], lq[4];
    int wid = tid >> 6;
    if ((tid & 63) == 0) { ls[wid] = s; lq[wid] = q; }
    __syncthreads();
    if (tid == 0) {
        s = ls[0] + ls[1] + ls[2] + ls[3];
        q = lq[0] + lq[1] + lq[2] + lq[3];
        float mean = s * (1.f / LL);
        float var = q * (1.f / LL) - mean * mean;
        stats[row * 2] = mean;
        stats[row * 2 + 1] = rsqrtf(var + 1e-5f);
    }
}

// ------------- instance-norm + mish apply (channel-major out) -------------
__global__ void napply(const float* __restrict__ y, const float* __restrict__ stats,
                       const float* __restrict__ gamma, const float* __restrict__ beta,
                       float* __restrict__ out) {
    int row = blockIdx.x;
    int co = row & (CO - 1);
    float mean = stats[row * 2], rstd = stats[row * 2 + 1];
    float scale = gamma[co] * rstd;
    float shift = beta[co] - mean * scale;
    const float4* p = (const float4*)(y + (size_t)row * LL);
    float4* o = (float4*)(out + (size_t)row * LL);
    for (int i = threadIdx.x; i < LL / 4; i += 256) {
        float4 v = p[i];
        v.x = mishf(fmaf(v.x, scale, shift));
        v.y = mishf(fmaf(v.y, scale, shift));
        v.z = mishf(fmaf(v.z, scale, shift));
        v.w = mishf(fmaf(v.w, scale, shift));
        o[i] = v;
    }
}

// ------------- downsample conv k=2 stride=2, tiled -------------
__global__ __launch_bounds__(256)
void conv_ds(const float* __restrict__ xs, const float* __restrict__ dw,
             float* __restrict__ xd) {
    __shared__ float x_lds[16][128];
    __shared__ float w_lds[16][2][64];
    int n = blockIdx.z, co0 = blockIdx.y * 64, lp0 = blockIdx.x * 64;
    int tid = threadIdx.x;
    int tl = tid & 31, tc = tid >> 5;
    float acc[8][2];
    #pragma unroll
    for (int c = 0; c < 8; c++) { acc[c][0] = 0.f; acc[c][1] = 0.f; }
    const float* xbase = xs + (size_t)n * CO * LL;
    for (int ci0 = 0; ci0 < CO; ci0 += 16) {
        for (int idx = tid; idx < 16 * 128; idx += 256) {
            int ci = idx >> 7, j = idx & 127;
            x_lds[ci][j] = xbase[(size_t)(ci0 + ci) * LL + 2 * lp0 + j];
        }
        for (int idx = tid; idx < 16 * 2 * 64; idx += 256) {
            int co = idx & 63;
            int rest = idx >> 6;
            int k = rest & 1, ci = rest >> 1;
            w_lds[ci][k][co] = dw[((size_t)(co0 + co) * CO + ci0 + ci) * 2 + k];
        }
        __syncthreads();
        #pragma unroll 4
        for (int ci = 0; ci < 16; ci++) {
            float xw[4];
            *(float4*)&xw[0] = *(const float4*)&x_lds[ci][tl * 4];
            #pragma unroll
            for (int k = 0; k < 2; k++) {
                float wv[8];
                *(float4*)&wv[0] = *(const float4*)&w_lds[ci][k][tc * 8];
                *(float4*)&wv[4] = *(const float4*)&w_lds[ci][k][tc * 8 + 4];
                #pragma unroll
                for (int c = 0; c < 8; c++) {
                    acc[c][0] = fmaf(wv[c], xw[0 + k], acc[c][0]);
                    acc[c][1] = fmaf(wv[c], xw[2 + k], acc[c][1]);
                }
            }
        }
        __syncthreads();
    }
    #pragma unroll
    for (int c = 0; c < 8; c++) {
        float2 v = make_float2(acc[c][0], acc[c][1]);
        *(float2*)&xd[((size_t)n * CO + co0 + tc * 8 + c) * LD + lp0 + tl * 2] = v;
    }
}

// ------------- per-channel BN stats over (N, LD) -------------
__global__ void colstat(const float* __restrict__ xd, float* __restrict__ stats) {
    int co = blockIdx.x;
    int tid = threadIdx.x;
    float s = 0.f, q = 0.f;
    for (int n = 0; n < NN; n++) {
        const float4* p = (const float4*)(xd + ((size_t)n * CO + co) * LD);
        for (int i = tid; i < LD / 4; i += 256) {
            float4 v = p[i];
            s += v.x + v.y + v.z + v.w;
            q += v.x * v.x + v.y * v.y + v.z * v.z + v.w * v.w;
        }
    }
    #pragma unroll
    for (int off = 32; off > 0; off >>= 1) {
        s += __shfl_down(s, off, 64);
        q += __shfl_down(q, off, 64);
    }
    __shared__ float ls[4], lq[4];
    int wid = tid >> 6;
    if ((tid & 63) == 0) { ls[wid] = s; lq[wid] = q; }
    __syncthreads();
    if (tid == 0) {
        s = ls[0] + ls[1] + ls[2] + ls[3];
        q = lq[0] + lq[1] + lq[2] + lq[3];
        const float cnt = (float)NN * LD;
        float mean = s / cnt;
        float var = q / cnt - mean * mean;
        stats[co * 2] = mean;
        stats[co * 2 + 1] = rsqrtf(var + 1e-5f);
    }
}

// ------------- BN + mish apply -------------
__global__ void bn_apply(const float* __restrict__ xd, const float* __restrict__ stats,
                         const float* __restrict__ dg, const float* __restrict__ db,
                         float* __restrict__ out) {
    int idx = blockIdx.x * 256 + threadIdx.x;
    if (idx >= NN * CO * LD / 4) return;
    int row = idx / (LD / 4);
    int co = row & (CO - 1);
    float mean = stats[co * 2], rstd = stats[co * 2 + 1];
    float scale = dg[co] * rstd;
    float shift = db[co] - mean * scale;
    float4 v = ((const float4*)xd)[idx];
    v.x = mishf(fmaf(v.x, scale, shift));
    v.y = mishf(fmaf(v.y, scale, shift));
    v.z = mishf(fmaf(v.z, scale, shift));
    v.w = mishf(fmaf(v.w, scale, shift));
    ((float4*)out)[idx] = v;
}

extern "C" void kernel_launch(void* const* d_in, const int* in_sizes, int n_in,
                              void* d_out, int out_size, void* d_ws, size_t ws_size,
                              hipStream_t stream) {
    const float* x     = (const float*)d_in[0];
    const float* t     = (const float*)d_in[1];
    const float* l1_k5 = (const float*)d_in[2];
    const float* l1_k3 = (const float*)d_in[3];
    const float* l1_k1 = (const float*)d_in[4];
    const float* l1_a3 = (const float*)d_in[5];
    const float* l1_a5 = (const float*)d_in[6];
    const float* l1_gw = (const float*)d_in[7];
    const float* l1_gb = (const float*)d_in[8];
    const float* l1_ga = (const float*)d_in[9];
    const float* l1_be = (const float*)d_in[10];
    const float* l2_k5 = (const float*)d_in[11];
    const float* l2_k3 = (const float*)d_in[12];
    const float* l2_k1 = (const float*)d_in[13];
    const float* l2_a3 = (const float*)d_in[14];
    const float* l2_a5 = (const float*)d_in[15];
    const float* l2_gw = (const float*)d_in[16];
    const float* l2_gb = (const float*)d_in[17];
    const float* l2_ga = (const float*)d_in[18];
    const float* l2_be = (const float*)d_in[19];
    const float* dwp   = (const float*)d_in[20];
    const float* dg    = (const float*)d_in[21];
    const float* db    = (const float*)d_in[22];
    float* out = (float*)d_out;

    float* ws = (float*)d_ws;
    float* g1  = ws;                       // 20480
    float* g2  = ws + 20480;               // 20480
    float* w1  = ws + 40960;               // 1310720
    float* w2  = ws + 1351680;             // 2621440
    float* st1 = ws + 3973120;             // 8192
    float* st2 = ws + 3981312;             // 8192
    float* stb = ws + 3989504;             // 256
    float* A   = ws + 4194304;             // 16777216 (xT, later xd_raw)
    float* B   = A + 16777216;             // 33554432 (y1, later y2)
    float* Cb  = B + 33554432;             // 33554432 (h, later x_skip cm)

    const size_t XD_ELEMS = (size_t)NN * CO * LD;  // 16777216

    // 1. gates
    gates_kernel<<<(2 * NN * CO + 255) / 256, 256, 0, stream>>>(t, l1_gw, l1_gb, l2_gw, l2_gb, g1, g2);
    // 2. per-sample weights
    weights_kernel<CI1><<<(NN * CI1 * CO + 255) / 256, 256, 0, stream>>>(g1, l1_k5, l1_k3, l1_k1, l1_a3, l1_a5, w1);
    weights_kernel<CO><<<(NN * CO * CO + 255) / 256, 256, 0, stream>>>(g2, l2_k5, l2_k3, l2_k1, l2_a3, l2_a5, w2);
    // 3. transpose x -> (N,Ci,L)
    transpose_in<CI1><<<dim3(LL / 64, CI1 / 64, NN), 256, 0, stream>>>(x, A);
    // 4. layer-1 conv
    conv_mode<CI1><<<dim3(LL / 128, CO / 64, NN), 256, 0, stream>>>(A, w1, B);
    // 5. layer-1 instance-norm stats + apply (-> h in Cb)
    rowstat<<<NN * CO, 256, 0, stream>>>(B, st1);
    napply<<<NN * CO, 256, 0, stream>>>(B, st1, l1_ga, l1_be, Cb);
    // 6. layer-2 conv (reads Cb, writes B)
    conv_mode<CO><<<dim3(LL / 128, CO / 64, NN), 256, 0, stream>>>(Cb, w2, B);
    // 7. layer-2 instance-norm stats + apply (-> x_skip cm in Cb)
    rowstat<<<NN * CO, 256, 0, stream>>>(B, st2);
    napply<<<NN * CO, 256, 0, stream>>>(B, st2, l2_ga, l2_be, Cb);
    // 8. x_skip transposed to d_out second slot (N,L,CO)
    transpose_out<<<dim3(LL / 64, CO / 64, NN), 256, 0, stream>>>(Cb, out + XD_ELEMS);
    // 9. downsample conv (reads Cb, writes A)
    conv_ds<<<dim3(LD / 64, CO / 64, NN), 256, 0, stream>>>(Cb, dwp, A);
    // 10. BN stats + apply -> d_out first slot (N,CO,LD)
    colstat<<<CO, 256, 0, stream>>>(A, stb);
    bn_apply<<<(int)((XD_ELEMS / 4 + 255) / 256), 256, 0, stream>>>(A, stb, dg, db, out);
}

// Round 2
// 976.666 us; speedup vs baseline: 1.7559x; 1.7559x over previous
//
#include <hip/hip_runtime.h>
#include <math.h>

#define NN 32
#define LL 8192
#define CI1 64
#define CO 128
#define KK 5
#define TT 10
#define EE 5
#define LD (LL/2)

typedef __attribute__((ext_vector_type(8))) short bf16x8;
typedef __attribute__((ext_vector_type(4))) float f32x4;

__device__ __forceinline__ unsigned short bf16_rne(float f) {
    unsigned u = __float_as_uint(f);
    unsigned r = (u + 0x7fffu + ((u >> 16) & 1u)) >> 16;
    return (unsigned short)r;
}
__device__ __forceinline__ float bf16_to_f(unsigned short h) {
    return __uint_as_float(((unsigned)h) << 16);
}
__device__ __forceinline__ float mishf(float x) {
    float sp = (x > 20.f) ? x : log1pf(expf(x));
    return x * tanhf(sp);
}

// ---------------- gates: softmax over experts ----------------
__global__ void gates_kernel(const float* __restrict__ t,
                             const float* __restrict__ gw1, const float* __restrict__ gb1,
                             const float* __restrict__ gw2, const float* __restrict__ gb2,
                             float* __restrict__ g1, float* __restrict__ g2) {
    int idx = blockIdx.x * blockDim.x + threadIdx.x;
    if (idx >= 2 * NN * CO) return;
    int layer = idx / (NN * CO);
    int r = idx % (NN * CO);
    int n = r / CO, co = r % CO;
    const float* gw = layer ? gw2 : gw1;
    const float* gb = layer ? gb2 : gb1;
    float* g = layer ? g2 : g1;
    float tv[TT];
    #pragma unroll
    for (int i = 0; i < TT; i++) tv[i] = t[n * TT + i];
    float lg[EE];
    float m = -1e30f;
    #pragma unroll
    for (int e = 0; e < EE; e++) {
        int row = e * CO + co;
        float s = gb[row];
        #pragma unroll
        for (int i = 0; i < TT; i++) s = fmaf(tv[i], gw[row * TT + i], s);
        lg[e] = s;
        m = fmaxf(m, s);
    }
    float den = 0.f;
    #pragma unroll
    for (int e = 0; e < EE; e++) { lg[e] = expf(lg[e] - m); den += lg[e]; }
    float inv = 1.f / den;
    #pragma unroll
    for (int e = 0; e < EE; e++) g[(n * EE + e) * CO + co] = lg[e] * inv;
}

// ------------- per-sample mixed kernels -> bf16 hi/lo planes [n][t][k][co][ci] -------------
template <int CI>
__global__ void weights_prep(const float* __restrict__ g,
                             const float* __restrict__ k5, const float* __restrict__ k3,
                             const float* __restrict__ k1, const float* __restrict__ a3,
                             const float* __restrict__ a5, unsigned short* __restrict__ wb) {
    int idx = blockIdx.x * blockDim.x + threadIdx.x;
    if (idx >= NN * CI * CO) return;
    int ci = idx % CI;
    int co = (idx / CI) % CO;
    int n = idx / (CI * CO);
    float gg[EE];
    #pragma unroll
    for (int e = 0; e < EE; e++) gg[e] = g[(n * EE + e) * CO + co];
    int b = co * CI + ci;
    float wv[KK];
    float aa3 = a3[b] * (1.f / 3.f) * gg[3];
    float aa5 = a5[b] * (1.f / 5.f) * gg[4];
    #pragma unroll
    for (int k = 0; k < KK; k++) wv[k] = gg[0] * k5[b * KK + k] + aa5;
    #pragma unroll
    for (int k = 0; k < 3; k++) wv[k + 2] += fmaf(gg[1], k3[b * 3 + k], aa3);
    wv[4] += gg[2] * k1[b];
    #pragma unroll
    for (int k = 0; k < KK; k++) {
        unsigned short hi = bf16_rne(wv[k]);
        unsigned short lo = bf16_rne(wv[k] - bf16_to_f(hi));
        size_t base = (size_t)(CO * CI);
        wb[((size_t)(n * 2 + 0) * KK + k) * base + b] = hi;
        wb[((size_t)(n * 2 + 1) * KK + k) * base + b] = lo;
    }
}

// ------------- downsample weights -> bf16 hi/lo planes [t][k][co][ci] -------------
__global__ void dsw_prep(const float* __restrict__ dw, unsigned short* __restrict__ dwb) {
    int idx = blockIdx.x * blockDim.x + threadIdx.x;
    if (idx >= CO * CO) return;
    int ci = idx % CO, co = idx / CO;
    #pragma unroll
    for (int k = 0; k < 2; k++) {
        float v = dw[(size_t)(co * CO + ci) * 2 + k];
        unsigned short hi = bf16_rne(v);
        unsigned short lo = bf16_rne(v - bf16_to_f(hi));
        dwb[((size_t)(0 * 2 + k) * CO + co) * CO + ci] = hi;
        dwb[((size_t)(2 + k) * CO + co) * CO + ci] = lo;
    }
}

// ------------- MFMA mode-conv: block 128co x 128l, fused IN partial stats -------------
// x layout (N,L,CI) channel-contiguous (fp32 or bf16 hi/lo planes)
// w layout [n][t][k][co][ci], output y (N,L,CO) fp32, partials ps/pq [n][co][64]
template <int CI, bool F32IN>
__global__ __launch_bounds__(256)
void conv_mfma(const float* __restrict__ xf,
               const unsigned short* __restrict__ xh, const unsigned short* __restrict__ xl,
               const unsigned short* __restrict__ wb,
               float* __restrict__ y, float* __restrict__ ps, float* __restrict__ pq) {
    __shared__ __align__(16) char lds[2 * 16896];
    __shared__ float red_s[2][CO], red_q[2][CO];
    const int n = blockIdx.z;
    const int l0 = blockIdx.x * 128;
    const int tid = threadIdx.x;
    const int lane = tid & 63;
    const int w = tid >> 6;
    const int wco = (w >> 1) * 64;
    const int wl = (w & 1) * 64;
    const int c = lane & 15, g = lane >> 4;

    f32x4 acc[4][4];
    #pragma unroll
    for (int i = 0; i < 4; i++)
        #pragma unroll
        for (int j = 0; j < 4; j++) {
            f32x4 z = {0.f, 0.f, 0.f, 0.f};
            acc[i][j] = z;
        }

    const unsigned short* wn = wb + (size_t)n * (2 * KK * CO * CI);

    for (int ci0 = 0; ci0 < CI; ci0 += 64) {
        __syncthreads();
        // stage x tile rows [l0-4, l0+128) x 64 ci, hi/lo planes, XOR-swizzled
        for (int slot = tid; slot < 132 * 8; slot += 256) {
            int row = slot >> 3, oct = slot & 7;
            int l = l0 - 4 + row;
            int dst = row * 128 + ((oct ^ (row & 7)) << 4);
            unsigned vh[4], vl[4];
            if (F32IN) {
                float f[8];
                if (l >= 0) {
                    const float* src = xf + ((size_t)n * LL + l) * CI + ci0 + oct * 8;
                    *(float4*)&f[0] = *(const float4*)src;
                    *(float4*)&f[4] = *(const float4*)(src + 4);
                } else {
                    #pragma unroll
                    for (int e = 0; e < 8; e++) f[e] = 0.f;
                }
                #pragma unroll
                for (int e = 0; e < 4; e++) {
                    unsigned short h0 = bf16_rne(f[2 * e]);
                    unsigned short h1 = bf16_rne(f[2 * e + 1]);
                    unsigned short q0 = bf16_rne(f[2 * e] - bf16_to_f(h0));
                    unsigned short q1 = bf16_rne(f[2 * e + 1] - bf16_to_f(h1));
                    vh[e] = (unsigned)h0 | ((unsigned)h1 << 16);
                    vl[e] = (unsigned)q0 | ((unsigned)q1 << 16);
                }
                *(uint4*)&lds[dst] = make_uint4(vh[0], vh[1], vh[2], vh[3]);
                *(uint4*)&lds[16896 + dst] = make_uint4(vl[0], vl[1], vl[2], vl[3]);
            } else {
                uint4 uh = make_uint4(0, 0, 0, 0), ul = make_uint4(0, 0, 0, 0);
                if (l >= 0) {
                    size_t off = ((size_t)n * LL + l) * CI + ci0 + oct * 8;
                    uh = *(const uint4*)(xh + off);
                    ul = *(const uint4*)(xl + off);
                }
                *(uint4*)&lds[dst] = uh;
                *(uint4*)&lds[16896 + dst] = ul;
            }
        }
        __syncthreads();
        #pragma unroll
        for (int k = 0; k < KK; k++) {
            #pragma unroll
            for (int ci32 = 0; ci32 < 2; ci32++) {
                bf16x8 Bh[4], Bl[4], Ah[4], Al[4];
                #pragma unroll
                for (int j = 0; j < 4; j++) {
                    int row = wl + j * 16 + c + k;
                    int addr = row * 128 + (((ci32 * 4 + g) ^ (row & 7)) << 4);
                    Bh[j] = *(const bf16x8*)&lds[addr];
                    Bl[j] = *(const bf16x8*)&lds[16896 + addr];
                }
                const unsigned short* wk = wn + (size_t)k * (CO * CI) + ci0 + ci32 * 32 + g * 8;
                #pragma unroll
                for (int i = 0; i < 4; i++) {
                    int co = wco + i * 16 + c;
                    Ah[i] = *(const bf16x8*)(wk + (size_t)co * CI);
                    Al[i] = *(const bf16x8*)(wk + (size_t)KK * CO * CI + (size_t)co * CI);
                }
                #pragma unroll
                for (int i = 0; i < 4; i++)
                    #pragma unroll
                    for (int j = 0; j < 4; j++) {
                        acc[i][j] = __builtin_amdgcn_mfma_f32_16x16x32_bf16(Ah[i], Bh[j], acc[i][j], 0, 0, 0);
                        acc[i][j] = __builtin_amdgcn_mfma_f32_16x16x32_bf16(Ah[i], Bl[j], acc[i][j], 0, 0, 0);
                        acc[i][j] = __builtin_amdgcn_mfma_f32_16x16x32_bf16(Al[i], Bh[j], acc[i][j], 0, 0, 0);
                    }
            }
        }
    }
    // fused instance-norm partial stats (per co over this block's 128 l)
    #pragma unroll
    for (int i = 0; i < 4; i++) {
        #pragma unroll
        for (int r = 0; r < 4; r++) {
            float s = 0.f, q = 0.f;
            #pragma unroll
            for (int j = 0; j < 4; j++) { float v = acc[i][j][r]; s += v; q += v * v; }
            #pragma unroll
            for (int m = 1; m < 16; m <<= 1) { s += __shfl_xor(s, m); q += __shfl_xor(q, m); }
            if (c == 0) {
                int col = wco + i * 16 + g * 4 + r;
                red_s[w & 1][col] = s;
                red_q[w & 1][col] = q;
            }
        }
    }
    __syncthreads();
    if (tid < CO) {
        float S = red_s[0][tid] + red_s[1][tid];
        float Q = red_q[0][tid] + red_q[1][tid];
        ps[((size_t)n * CO + tid) * 64 + blockIdx.x] = S;
        pq[((size_t)n * CO + tid) * 64 + blockIdx.x] = Q;
    }
    // y store: (N,L,CO) l-major, float4 per (i,j)
    #pragma unroll
    for (int i = 0; i < 4; i++)
        #pragma unroll
        for (int j = 0; j < 4; j++) {
            int l = l0 + wl + j * 16 + c;
            int co = wco + i * 16 + g * 4;
            *(f32x4*)&y[((size_t)n * LL + l) * CO + co] = acc[i][j];
        }
}

// ------------- reduce partials -> per-(n,co) scale/shift -------------
__global__ void stats_reduce(const float* __restrict__ ps, const float* __restrict__ pq,
                             const float* __restrict__ gamma, const float* __restrict__ beta,
                             float* __restrict__ scale, float* __restrict__ shift) {
    int row = blockIdx.x;  // n*CO+co
    int tid = threadIdx.x; // 64
    float s = ps[(size_t)row * 64 + tid];
    float q = pq[(size_t)row * 64 + tid];
    #pragma unroll
    for (int m = 1; m < 64; m <<= 1) { s += __shfl_xor(s, m); q += __shfl_xor(q, m); }
    if (tid == 0) {
        float mean = s * (1.f / LL);
        float var = q * (1.f / LL) - mean * mean;
        float rstd = rsqrtf(var + 1e-5f);
        int co = row & (CO - 1);
        float sc = gamma[co] * rstd;
        scale[row] = sc;
        shift[row] = beta[co] - mean * sc;
    }
}

// ------------- instance-norm + mish apply; emit bf16 hi/lo planes (+fp32 final) -------------
template <bool FINAL>
__global__ void napply(const float* __restrict__ y, const float* __restrict__ scale,
                       const float* __restrict__ shift,
                       unsigned short* __restrict__ hh, unsigned short* __restrict__ hl,
                       float* __restrict__ outf) {
    size_t idx = (size_t)blockIdx.x * 256 + threadIdx.x;  // float4 units; total 8388608
    int co4 = (int)(idx & 31);
    int n = (int)(idx >> 18);
    f32x4 v = *(const f32x4*)&y[idx * 4];
    f32x4 sc = *(const f32x4*)&scale[(size_t)n * CO + co4 * 4];
    f32x4 sh = *(const f32x4*)&shift[(size_t)n * CO + co4 * 4];
    f32x4 o;
    #pragma unroll
    for (int e = 0; e < 4; e++) o[e] = mishf(fmaf(v[e], sc[e], sh[e]));
    ushort4 hi, lo;
    hi.x = bf16_rne(o[0]); lo.x = bf16_rne(o[0] - bf16_to_f(hi.x));
    hi.y = bf16_rne(o[1]); lo.y = bf16_rne(o[1] - bf16_to_f(hi.y));
    hi.z = bf16_rne(o[2]); lo.z = bf16_rne(o[2] - bf16_to_f(hi.z));
    hi.w = bf16_rne(o[3]); lo.w = bf16_rne(o[3] - bf16_to_f(hi.w));
    *(ushort4*)&hh[idx * 4] = hi;
    *(ushort4*)&hl[idx * 4] = lo;
    if (FINAL) *(f32x4*)&outf[idx * 4] = o;
}

// ------------- MFMA downsample conv k=2 stride=2, fused BN partial stats -------------
__global__ __launch_bounds__(256)
void conv_ds_mfma(const unsigned short* __restrict__ sh, const unsigned short* __restrict__ sl,
                  const unsigned short* __restrict__ dwb,
                  float* __restrict__ yds, float* __restrict__ ps, float* __restrict__ pq) {
    __shared__ __align__(16) char lds[2 * 16384];
    const int n = blockIdx.z;
    const int lp0 = blockIdx.x * 64;
    const int tid = threadIdx.x;
    const int lane = tid & 63, w = tid >> 6;
    const int wco = w * 32;
    const int c = lane & 15, g = lane >> 4;
    f32x4 acc[2][4];
    #pragma unroll
    for (int i = 0; i < 2; i++)
        #pragma unroll
        for (int j = 0; j < 4; j++) {
            f32x4 z = {0.f, 0.f, 0.f, 0.f};
            acc[i][j] = z;
        }
    for (int ci0 = 0; ci0 < CO; ci0 += 64) {
        __syncthreads();
        for (int slot = tid; slot < 128 * 8; slot += 256) {
            int row = slot >> 3, oct = slot & 7;
            int l = 2 * lp0 + row;
            int dst = row * 128 + ((oct ^ ((row >> 1) & 7)) << 4);
            size_t off = ((size_t)n * LL + l) * CO + ci0 + oct * 8;
            *(uint4*)&lds[dst] = *(const uint4*)(sh + off);
            *(uint4*)&lds[16384 + dst] = *(const uint4*)(sl + off);
        }
        __syncthreads();
        #pragma unroll
        for (int k = 0; k < 2; k++) {
            #pragma unroll
            for (int ci32 = 0; ci32 < 2; ci32++) {
                bf16x8 Bh[4], Bl[4], Ah[2], Al[2];
                #pragma unroll
                for (int j = 0; j < 4; j++) {
                    int row = 2 * (j * 16 + c) + k;
                    int addr = row * 128 + (((ci32 * 4 + g) ^ ((row >> 1) & 7)) << 4);
                    Bh[j] = *(const bf16x8*)&lds[addr];
                    Bl[j] = *(const bf16x8*)&lds[16384 + addr];
                }
                const unsigned short* wk = dwb + (size_t)k * (CO * CO) + ci0 + ci32 * 32 + g * 8;
                #pragma unroll
                for (int i = 0; i < 2; i++) {
                    int co = wco + i * 16 + c;
                    Ah[i] = *(const bf16x8*)(wk + (size_t)co * CO);
                    Al[i] = *(const bf16x8*)(wk + (size_t)2 * CO * CO + (size_t)co * CO);
                }
                #pragma unroll
                for (int i = 0; i < 2; i++)
                    #pragma unroll
                    for (int j = 0; j < 4; j++) {
                        acc[i][j] = __builtin_amdgcn_mfma_f32_16x16x32_bf16(Ah[i], Bh[j], acc[i][j], 0, 0, 0);
                        acc[i][j] = __builtin_amdgcn_mfma_f32_16x16x32_bf16(Ah[i], Bl[j], acc[i][j], 0, 0, 0);
                        acc[i][j] = __builtin_amdgcn_mfma_f32_16x16x32_bf16(Al[i], Bh[j], acc[i][j], 0, 0, 0);
                    }
            }
        }
    }
    // BN partials per co over this block's 64 lp (each wave owns unique 32 co)
    #pragma unroll
    for (int i = 0; i < 2; i++) {
        #pragma unroll
        for (int r = 0; r < 4; r++) {
            float s = 0.f, q = 0.f;
            #pragma unroll
            for (int j = 0; j < 4; j++) { float v = acc[i][j][r]; s += v; q += v * v; }
            #pragma unroll
            for (int m = 1; m < 16; m <<= 1) { s += __shfl_xor(s, m); q += __shfl_xor(q, m); }
            if (c == 0) {
                int co = wco + i * 16 + g * 4 + r;
                ps[(size_t)co * 2048 + n * 64 + blockIdx.x] = s;
                pq[(size_t)co * 2048 + n * 64 + blockIdx.x] = q;
            }
        }
    }
    // store yds (N,CO,LD)
    #pragma unroll
    for (int i = 0; i < 2; i++)
        #pragma unroll
        for (int j = 0; j < 4; j++) {
            int lp = lp0 + j * 16 + c;
            #pragma unroll
            for (int r = 0; r < 4; r++) {
                int co = wco + i * 16 + g * 4 + r;
                yds[((size_t)n * CO + co) * LD + lp] = acc[i][j][r];
            }
        }
}

// ------------- BN stats reduce -------------
__global__ void bnstats(const float* __restrict__ ps, const float* __restrict__ pq,
                        const float* __restrict__ dg, const float* __restrict__ db,
                        float* __restrict__ scale, float* __restrict__ shift) {
    int co = blockIdx.x;
    int tid = threadIdx.x;
    float s = 0.f, q = 0.f;
    #pragma unroll
    for (int it = 0; it < 8; it++) {
        s += ps[(size_t)co * 2048 + it * 256 + tid];
        q += pq[(size_t)co * 2048 + it * 256 + tid];
    }
    #pragma unroll
    for (int m = 1; m < 64; m <<= 1) { s += __shfl_xor(s, m); q += __shfl_xor(q, m); }
    __shared__ float a[4], b[4];
    if ((tid & 63) == 0) { a[tid >> 6] = s; b[tid >> 6] = q; }
    __syncthreads();
    if (tid == 0) {
        s = a[0] + a[1] + a[2] + a[3];
        q = b[0] + b[1] + b[2] + b[3];
        const float inv = 1.f / ((float)NN * (float)LD);
        float mean = s * inv;
        float var = q * inv - mean * mean;
        float rstd = rsqrtf(var + 1e-5f);
        float sc = dg[co] * rstd;
        scale[co] = sc;
        shift[co] = db[co] - mean * sc;
    }
}

// ------------- BN + mish apply -------------
__global__ void bn_apply(const float* __restrict__ yds, const float* __restrict__ scale,
                         const float* __restrict__ shift, float* __restrict__ out) {
    size_t idx = (size_t)blockIdx.x * 256 + threadIdx.x;  // float4; total 4194304
    int row = (int)(idx >> 10);
    int co = row & (CO - 1);
    float sc = scale[co], sf = shift[co];
    f32x4 v = *(const f32x4*)&yds[idx * 4];
    #pragma unroll
    for (int e = 0; e < 4; e++) v[e] = mishf(fmaf(v[e], sc, sf));
    *(f32x4*)&out[idx * 4] = v;
}

extern "C" void kernel_launch(void* const* d_in, const int* in_sizes, int n_in,
                              void* d_out, int out_size, void* d_ws, size_t ws_size,
                              hipStream_t stream) {
    const float* x     = (const float*)d_in[0];
    const float* t     = (const float*)d_in[1];
    const float* l1_k5 = (const float*)d_in[2];
    const float* l1_k3 = (const float*)d_in[3];
    const float* l1_k1 = (const float*)d_in[4];
    const float* l1_a3 = (const float*)d_in[5];
    const float* l1_a5 = (const float*)d_in[6];
    const float* l1_gw = (const float*)d_in[7];
    const float* l1_gb = (const float*)d_in[8];
    const float* l1_ga = (const float*)d_in[9];
    const float* l1_be = (const float*)d_in[10];
    const float* l2_k5 = (const float*)d_in[11];
    const float* l2_k3 = (const float*)d_in[12];
    const float* l2_k1 = (const float*)d_in[13];
    const float* l2_a3 = (const float*)d_in[14];
    const float* l2_a5 = (const float*)d_in[15];
    const float* l2_gw = (const float*)d_in[16];
    const float* l2_gb = (const float*)d_in[17];
    const float* l2_ga = (const float*)d_in[18];
    const float* l2_be = (const float*)d_in[19];
    const float* dwp   = (const float*)d_in[20];
    const float* dg    = (const float*)d_in[21];
    const float* db    = (const float*)d_in[22];
    float* out = (float*)d_out;

    float* ws = (float*)d_ws;
    size_t o = 0;
    float* g1 = ws + o; o += 20480;
    float* g2 = ws + o; o += 20480;
    unsigned short* w1b = (unsigned short*)(ws + o); o += (size_t)NN * 2 * KK * CO * CI1 / 2;  // 1310720
    unsigned short* w2b = (unsigned short*)(ws + o); o += (size_t)NN * 2 * KK * CO * CO / 2;   // 2621440
    unsigned short* dwb = (unsigned short*)(ws + o); o += (size_t)4 * CO * CO / 2;             // 32768
    float* ps = ws + o; o += 262144;
    float* pq = ws + o; o += 262144;
    float* scale1 = ws + o; o += 4096;
    float* shift1 = ws + o; o += 4096;
    float* scale2 = ws + o; o += 4096;
    float* shift2 = ws + o; o += 4096;
    float* scaled = ws + o; o += 128;
    float* shiftd = ws + o; o += 128;
    o = (o + 3) & ~(size_t)3;
    float* y = ws + o; o += (size_t)NN * LL * CO;                                              // 33554432
    unsigned short* hh = (unsigned short*)(ws + o); o += (size_t)NN * LL * CO / 2;             // 16777216
    unsigned short* hl = (unsigned short*)(ws + o); o += (size_t)NN * LL * CO / 2;

    const size_t XD_ELEMS = (size_t)NN * CO * LD;  // 16777216

    gates_kernel<<<(2 * NN * CO + 255) / 256, 256, 0, stream>>>(t, l1_gw, l1_gb, l2_gw, l2_gb, g1, g2);
    weights_prep<CI1><<<(NN * CI1 * CO + 255) / 256, 256, 0, stream>>>(g1, l1_k5, l1_k3, l1_k1, l1_a3, l1_a5, w1b);
    weights_prep<CO><<<(NN * CO * CO + 255) / 256, 256, 0, stream>>>(g2, l2_k5, l2_k3, l2_k1, l2_a3, l2_a5, w2b);
    dsw_prep<<<(CO * CO + 255) / 256, 256, 0, stream>>>(dwp, dwb);

    conv_mfma<CI1, true><<<dim3(LL / 128, 1, NN), 256, 0, stream>>>(x, nullptr, nullptr, w1b, y, ps, pq);
    stats_reduce<<<NN * CO, 64, 0, stream>>>(ps, pq, l1_ga, l1_be, scale1, shift1);
    napply<false><<<32768, 256, 0, stream>>>(y, scale1, shift1, hh, hl, nullptr);

    conv_mfma<CO, false><<<dim3(LL / 128, 1, NN), 256, 0, stream>>>(nullptr, hh, hl, w2b, y, ps, pq);
    stats_reduce<<<NN * CO, 64, 0, stream>>>(ps, pq, l2_ga, l2_be, scale2, shift2);
    napply<true><<<32768, 256, 0, stream>>>(y, scale2, shift2, hh, hl, out + XD_ELEMS);

    conv_ds_mfma<<<dim3(LD / 64, 1, NN), 256, 0, stream>>>(hh, hl, dwb, y, ps, pq);
    bnstats<<<CO, 256, 0, stream>>>(ps, pq, dg, db, scaled, shiftd);
    bn_apply<<<(int)(XD_ELEMS / 4 / 256), 256, 0, stream>>>(y, scaled, shiftd, out);
}

// Round 3
// 704.629 us; speedup vs baseline: 2.4338x; 1.3861x over previous
//
#include <hip/hip_runtime.h>
#include <math.h>

#define NN 32
#define LL 8192
#define CI1 64
#define CO 128
#define KK 5
#define TT 10
#define EE 5
#define LD (LL/2)

typedef __attribute__((ext_vector_type(8))) short bf16x8;
typedef __attribute__((ext_vector_type(4))) float f32x4;

__device__ __forceinline__ unsigned short bf16_rne(float f) {
    unsigned u = __float_as_uint(f);
    unsigned r = (u + 0x7fffu + ((u >> 16) & 1u)) >> 16;
    return (unsigned short)r;
}
__device__ __forceinline__ float bf16_to_f(unsigned short h) {
    return __uint_as_float(((unsigned)h) << 16);
}
// mish(x) = x * tanh(softplus(x)) = x*(w^2-1)/(w^2+1), w = 1+e^x  (exact identity)
__device__ __forceinline__ float mishf(float x) {
    float e = __expf(x);
    float w = 1.f + e;
    float w2 = w * w;
    float r = x * (w2 - 1.f) / (w2 + 1.f);
    return (x > 15.f) ? x : r;
}

// ---------------- gates: softmax over experts ----------------
__global__ void gates_kernel(const float* __restrict__ t,
                             const float* __restrict__ gw1, const float* __restrict__ gb1,
                             const float* __restrict__ gw2, const float* __restrict__ gb2,
                             float* __restrict__ g1, float* __restrict__ g2) {
    int idx = blockIdx.x * blockDim.x + threadIdx.x;
    if (idx >= 2 * NN * CO) return;
    int layer = idx / (NN * CO);
    int r = idx % (NN * CO);
    int n = r / CO, co = r % CO;
    const float* gw = layer ? gw2 : gw1;
    const float* gb = layer ? gb2 : gb1;
    float* g = layer ? g2 : g1;
    float tv[TT];
    #pragma unroll
    for (int i = 0; i < TT; i++) tv[i] = t[n * TT + i];
    float lg[EE];
    float m = -1e30f;
    #pragma unroll
    for (int e = 0; e < EE; e++) {
        int row = e * CO + co;
        float s = gb[row];
        #pragma unroll
        for (int i = 0; i < TT; i++) s = fmaf(tv[i], gw[row * TT + i], s);
        lg[e] = s;
        m = fmaxf(m, s);
    }
    float den = 0.f;
    #pragma unroll
    for (int e = 0; e < EE; e++) { lg[e] = expf(lg[e] - m); den += lg[e]; }
    float inv = 1.f / den;
    #pragma unroll
    for (int e = 0; e < EE; e++) g[(n * EE + e) * CO + co] = lg[e] * inv;
}

// ------- per-sample mixed kernels -> packed fragment-major bf16 hi/lo -------
// element (n, plane, k, ciblk, co, g, e):
//   addr = (((((n*2+plane)*KK + k)*(CI/32) + ciblk)*CO + co) << 5) + (g<<3) + e
// so a wave's A-fragment load (lane=(g<<4)|c reads co=base+c, ci-octet g) is
// one contiguous, fully-coalesced 1024B region.
template <int CI>
__global__ void weights_prep(const float* __restrict__ g,
                             const float* __restrict__ k5, const float* __restrict__ k3,
                             const float* __restrict__ k1, const float* __restrict__ a3,
                             const float* __restrict__ a5, unsigned short* __restrict__ wb) {
    int idx = blockIdx.x * blockDim.x + threadIdx.x;
    if (idx >= NN * CI * CO) return;
    int ci = idx % CI;
    int co = (idx / CI) % CO;
    int n = idx / (CI * CO);
    const int NCI32 = CI / 32;
    float gg[EE];
    #pragma unroll
    for (int e = 0; e < EE; e++) gg[e] = g[(n * EE + e) * CO + co];
    int b = co * CI + ci;
    float wv[KK];
    float aa3 = a3[b] * (1.f / 3.f) * gg[3];
    float aa5 = a5[b] * (1.f / 5.f) * gg[4];
    #pragma unroll
    for (int k = 0; k < KK; k++) wv[k] = gg[0] * k5[b * KK + k] + aa5;
    #pragma unroll
    for (int k = 0; k < 3; k++) wv[k + 2] += fmaf(gg[1], k3[b * 3 + k], aa3);
    wv[4] += gg[2] * k1[b];
    int sub = (((ci >> 3) & 3) << 3) + (ci & 7);
    #pragma unroll
    for (int k = 0; k < KK; k++) {
        unsigned short hi = bf16_rne(wv[k]);
        unsigned short lo = bf16_rne(wv[k] - bf16_to_f(hi));
        size_t a0 = ((((size_t)(n * 2 + 0) * KK + k) * NCI32 + (ci >> 5)) * CO + co) * 32 + sub;
        size_t a1 = ((((size_t)(n * 2 + 1) * KK + k) * NCI32 + (ci >> 5)) * CO + co) * 32 + sub;
        wb[a0] = hi;
        wb[a1] = lo;
    }
}

// ------- downsample weights -> packed fragment-major, (plane,k,ciblk,co,g,e) -------
__global__ void dsw_prep(const float* __restrict__ dw, unsigned short* __restrict__ dwb) {
    int idx = blockIdx.x * blockDim.x + threadIdx.x;
    if (idx >= CO * CO) return;
    int ci = idx % CO, co = idx / CO;
    int sub = (((ci >> 3) & 3) << 3) + (ci & 7);
    #pragma unroll
    for (int k = 0; k < 2; k++) {
        float v = dw[(size_t)(co * CO + ci) * 2 + k];
        unsigned short hi = bf16_rne(v);
        unsigned short lo = bf16_rne(v - bf16_to_f(hi));
        dwb[(((size_t)(0 * 2 + k) * 4 + (ci >> 5)) * CO + co) * 32 + sub] = hi;
        dwb[(((size_t)(1 * 2 + k) * 4 + (ci >> 5)) * CO + co) * 32 + sub] = lo;
    }
}

// ------------- MFMA mode-conv: block 128co x 128l, fused IN partial stats -------------
template <int CI, bool F32IN>
__global__ __launch_bounds__(256)
void conv_mfma(const float* __restrict__ xf,
               const unsigned short* __restrict__ xh, const unsigned short* __restrict__ xl,
               const unsigned short* __restrict__ wb,
               float* __restrict__ y, float* __restrict__ ps, float* __restrict__ pq) {
    __shared__ __align__(16) char lds[2 * 16896];
    __shared__ float red_s[2][CO], red_q[2][CO];
    const int n = blockIdx.z;
    const int l0 = blockIdx.x * 128;
    const int tid = threadIdx.x;
    const int lane = tid & 63;
    const int w = tid >> 6;
    const int wco = (w >> 1) * 64;
    const int wl = (w & 1) * 64;
    const int c = lane & 15, g = lane >> 4;
    const int NCI32 = CI / 32;

    f32x4 acc[4][4];
    #pragma unroll
    for (int i = 0; i < 4; i++)
        #pragma unroll
        for (int j = 0; j < 4; j++) {
            f32x4 z = {0.f, 0.f, 0.f, 0.f};
            acc[i][j] = z;
        }

    const unsigned short* wn = wb + (size_t)n * (2 * KK * CO * CI);

    for (int ci0 = 0; ci0 < CI; ci0 += 64) {
        __syncthreads();
        for (int slot = tid; slot < 132 * 8; slot += 256) {
            int row = slot >> 3, oct = slot & 7;
            int l = l0 - 4 + row;
            int dst = row * 128 + ((oct ^ (row & 7)) << 4);
            if (F32IN) {
                unsigned vh[4], vl[4];
                float f[8];
                if (l >= 0) {
                    const float* src = xf + ((size_t)n * LL + l) * CI + ci0 + oct * 8;
                    *(float4*)&f[0] = *(const float4*)src;
                    *(float4*)&f[4] = *(const float4*)(src + 4);
                } else {
                    #pragma unroll
                    for (int e = 0; e < 8; e++) f[e] = 0.f;
                }
                #pragma unroll
                for (int e = 0; e < 4; e++) {
                    unsigned short h0 = bf16_rne(f[2 * e]);
                    unsigned short h1 = bf16_rne(f[2 * e + 1]);
                    unsigned short q0 = bf16_rne(f[2 * e] - bf16_to_f(h0));
                    unsigned short q1 = bf16_rne(f[2 * e + 1] - bf16_to_f(h1));
                    vh[e] = (unsigned)h0 | ((unsigned)h1 << 16);
                    vl[e] = (unsigned)q0 | ((unsigned)q1 << 16);
                }
                *(uint4*)&lds[dst] = make_uint4(vh[0], vh[1], vh[2], vh[3]);
                *(uint4*)&lds[16896 + dst] = make_uint4(vl[0], vl[1], vl[2], vl[3]);
            } else {
                uint4 uh = make_uint4(0, 0, 0, 0), ul = make_uint4(0, 0, 0, 0);
                if (l >= 0) {
                    size_t off = ((size_t)n * LL + l) * CI + ci0 + oct * 8;
                    uh = *(const uint4*)(xh + off);
                    ul = *(const uint4*)(xl + off);
                }
                *(uint4*)&lds[dst] = uh;
                *(uint4*)&lds[16896 + dst] = ul;
            }
        }
        __syncthreads();
        #pragma unroll
        for (int k = 0; k < KK; k++) {
            #pragma unroll
            for (int ci32 = 0; ci32 < 2; ci32++) {
                const int ciblk = (ci0 >> 5) + ci32;
                bf16x8 Bh[4], Bl[4], Ah[4], Al[4];
                #pragma unroll
                for (int j = 0; j < 4; j++) {
                    int row = wl + j * 16 + c + k;
                    int addr = row * 128 + (((ci32 * 4 + g) ^ (row & 7)) << 4);
                    Bh[j] = *(const bf16x8*)&lds[addr];
                    Bl[j] = *(const bf16x8*)&lds[16896 + addr];
                }
                #pragma unroll
                for (int i = 0; i < 4; i++) {
                    size_t ah = ((((size_t)0 * KK + k) * NCI32 + ciblk) * CO + wco + i * 16 + c) * 32 + g * 8;
                    size_t al = ((((size_t)1 * KK + k) * NCI32 + ciblk) * CO + wco + i * 16 + c) * 32 + g * 8;
                    Ah[i] = *(const bf16x8*)(wn + ah);
                    Al[i] = *(const bf16x8*)(wn + al);
                }
                #pragma unroll
                for (int i = 0; i < 4; i++)
                    #pragma unroll
                    for (int j = 0; j < 4; j++) {
                        acc[i][j] = __builtin_amdgcn_mfma_f32_16x16x32_bf16(Ah[i], Bh[j], acc[i][j], 0, 0, 0);
                        acc[i][j] = __builtin_amdgcn_mfma_f32_16x16x32_bf16(Ah[i], Bl[j], acc[i][j], 0, 0, 0);
                        acc[i][j] = __builtin_amdgcn_mfma_f32_16x16x32_bf16(Al[i], Bh[j], acc[i][j], 0, 0, 0);
                    }
            }
        }
    }
    // fused instance-norm partial stats
    #pragma unroll
    for (int i = 0; i < 4; i++) {
        #pragma unroll
        for (int r = 0; r < 4; r++) {
            float s = 0.f, q = 0.f;
            #pragma unroll
            for (int j = 0; j < 4; j++) { float v = acc[i][j][r]; s += v; q += v * v; }
            #pragma unroll
            for (int m = 1; m < 16; m <<= 1) { s += __shfl_xor(s, m); q += __shfl_xor(q, m); }
            if (c == 0) {
                int col = wco + i * 16 + g * 4 + r;
                red_s[w & 1][col] = s;
                red_q[w & 1][col] = q;
            }
        }
    }
    __syncthreads();
    if (tid < CO) {
        float S = red_s[0][tid] + red_s[1][tid];
        float Q = red_q[0][tid] + red_q[1][tid];
        ps[((size_t)n * CO + tid) * 64 + blockIdx.x] = S;
        pq[((size_t)n * CO + tid) * 64 + blockIdx.x] = Q;
    }
    #pragma unroll
    for (int i = 0; i < 4; i++)
        #pragma unroll
        for (int j = 0; j < 4; j++) {
            int l = l0 + wl + j * 16 + c;
            int co = wco + i * 16 + g * 4;
            *(f32x4*)&y[((size_t)n * LL + l) * CO + co] = acc[i][j];
        }
}

// ------------- reduce partials -> per-(n,co) scale/shift -------------
__global__ void stats_reduce(const float* __restrict__ ps, const float* __restrict__ pq,
                             const float* __restrict__ gamma, const float* __restrict__ beta,
                             float* __restrict__ scale, float* __restrict__ shift) {
    int row = blockIdx.x;
    int tid = threadIdx.x;
    float s = ps[(size_t)row * 64 + tid];
    float q = pq[(size_t)row * 64 + tid];
    #pragma unroll
    for (int m = 1; m < 64; m <<= 1) { s += __shfl_xor(s, m); q += __shfl_xor(q, m); }
    if (tid == 0) {
        float mean = s * (1.f / LL);
        float var = q * (1.f / LL) - mean * mean;
        float rstd = rsqrtf(var + 1e-5f);
        int co = row & (CO - 1);
        float sc = gamma[co] * rstd;
        scale[row] = sc;
        shift[row] = beta[co] - mean * sc;
    }
}

// ------- instance-norm + mish apply; FINAL: fp32 only; else bf16 hi/lo planes -------
template <bool FINAL>
__global__ void napply(const float* __restrict__ y, const float* __restrict__ scale,
                       const float* __restrict__ shift,
                       unsigned short* __restrict__ hh, unsigned short* __restrict__ hl,
                       float* __restrict__ outf) {
    size_t idx = (size_t)blockIdx.x * 256 + threadIdx.x;
    int co4 = (int)(idx & 31);
    int n = (int)(idx >> 18);
    f32x4 v = *(const f32x4*)&y[idx * 4];
    f32x4 sc = *(const f32x4*)&scale[(size_t)n * CO + co4 * 4];
    f32x4 sh = *(const f32x4*)&shift[(size_t)n * CO + co4 * 4];
    f32x4 o;
    #pragma unroll
    for (int e = 0; e < 4; e++) o[e] = mishf(fmaf(v[e], sc[e], sh[e]));
    if (FINAL) {
        *(f32x4*)&outf[idx * 4] = o;
    } else {
        ushort4 hi, lo;
        hi.x = bf16_rne(o[0]); lo.x = bf16_rne(o[0] - bf16_to_f(hi.x));
        hi.y = bf16_rne(o[1]); lo.y = bf16_rne(o[1] - bf16_to_f(hi.y));
        hi.z = bf16_rne(o[2]); lo.z = bf16_rne(o[2] - bf16_to_f(hi.z));
        hi.w = bf16_rne(o[3]); lo.w = bf16_rne(o[3] - bf16_to_f(hi.w));
        *(ushort4*)&hh[idx * 4] = hi;
        *(ushort4*)&hl[idx * 4] = lo;
    }
}

// ------- MFMA downsample conv k=2 s=2 from fp32 x_skip, fused BN partials -------
__global__ __launch_bounds__(256)
void conv_ds_mfma(const float* __restrict__ xs, const unsigned short* __restrict__ dwb,
                  float* __restrict__ yds, float* __restrict__ ps, float* __restrict__ pq) {
    __shared__ __align__(16) char lds[2 * 16384];
    const int n = blockIdx.z;
    const int lp0 = blockIdx.x * 64;
    const int tid = threadIdx.x;
    const int lane = tid & 63, w = tid >> 6;
    const int wco = w * 32;
    const int c = lane & 15, g = lane >> 4;
    f32x4 acc[2][4];
    #pragma unroll
    for (int i = 0; i < 2; i++)
        #pragma unroll
        for (int j = 0; j < 4; j++) {
            f32x4 z = {0.f, 0.f, 0.f, 0.f};
            acc[i][j] = z;
        }
    for (int ci0 = 0; ci0 < CO; ci0 += 64) {
        __syncthreads();
        for (int slot = tid; slot < 128 * 8; slot += 256) {
            int row = slot >> 3, oct = slot & 7;
            int l = 2 * lp0 + row;
            int dst = row * 128 + ((oct ^ ((row >> 1) & 7)) << 4);
            const float* src = xs + ((size_t)n * LL + l) * CO + ci0 + oct * 8;
            float f[8];
            *(float4*)&f[0] = *(const float4*)src;
            *(float4*)&f[4] = *(const float4*)(src + 4);
            unsigned vh[4], vl[4];
            #pragma unroll
            for (int e = 0; e < 4; e++) {
                unsigned short h0 = bf16_rne(f[2 * e]);
                unsigned short h1 = bf16_rne(f[2 * e + 1]);
                unsigned short q0 = bf16_rne(f[2 * e] - bf16_to_f(h0));
                unsigned short q1 = bf16_rne(f[2 * e + 1] - bf16_to_f(h1));
                vh[e] = (unsigned)h0 | ((unsigned)h1 << 16);
                vl[e] = (unsigned)q0 | ((unsigned)q1 << 16);
            }
            *(uint4*)&lds[dst] = make_uint4(vh[0], vh[1], vh[2], vh[3]);
            *(uint4*)&lds[16384 + dst] = make_uint4(vl[0], vl[1], vl[2], vl[3]);
        }
        __syncthreads();
        #pragma unroll
        for (int k = 0; k < 2; k++) {
            #pragma unroll
            for (int ci32 = 0; ci32 < 2; ci32++) {
                const int ciblk = (ci0 >> 5) + ci32;
                bf16x8 Bh[4], Bl[4], Ah[2], Al[2];
                #pragma unroll
                for (int j = 0; j < 4; j++) {
                    int row = 2 * (j * 16 + c) + k;
                    int addr = row * 128 + (((ci32 * 4 + g) ^ ((row >> 1) & 7)) << 4);
                    Bh[j] = *(const bf16x8*)&lds[addr];
                    Bl[j] = *(const bf16x8*)&lds[16384 + addr];
                }
                #pragma unroll
                for (int i = 0; i < 2; i++) {
                    size_t ah = (((size_t)(0 * 2 + k) * 4 + ciblk) * CO + wco + i * 16 + c) * 32 + g * 8;
                    size_t al = (((size_t)(1 * 2 + k) * 4 + ciblk) * CO + wco + i * 16 + c) * 32 + g * 8;
                    Ah[i] = *(const bf16x8*)(dwb + ah);
                    Al[i] = *(const bf16x8*)(dwb + al);
                }
                #pragma unroll
                for (int i = 0; i < 2; i++)
                    #pragma unroll
                    for (int j = 0; j < 4; j++) {
                        acc[i][j] = __builtin_amdgcn_mfma_f32_16x16x32_bf16(Ah[i], Bh[j], acc[i][j], 0, 0, 0);
                        acc[i][j] = __builtin_amdgcn_mfma_f32_16x16x32_bf16(Ah[i], Bl[j], acc[i][j], 0, 0, 0);
                        acc[i][j] = __builtin_amdgcn_mfma_f32_16x16x32_bf16(Al[i], Bh[j], acc[i][j], 0, 0, 0);
                    }
            }
        }
    }
    #pragma unroll
    for (int i = 0; i < 2; i++) {
        #pragma unroll
        for (int r = 0; r < 4; r++) {
            float s = 0.f, q = 0.f;
            #pragma unroll
            for (int j = 0; j < 4; j++) { float v = acc[i][j][r]; s += v; q += v * v; }
            #pragma unroll
            for (int m = 1; m < 16; m <<= 1) { s += __shfl_xor(s, m); q += __shfl_xor(q, m); }
            if (c == 0) {
                int co = wco + i * 16 + g * 4 + r;
                ps[(size_t)co * 2048 + n * 64 + blockIdx.x] = s;
                pq[(size_t)co * 2048 + n * 64 + blockIdx.x] = q;
            }
        }
    }
    #pragma unroll
    for (int i = 0; i < 2; i++)
        #pragma unroll
        for (int j = 0; j < 4; j++) {
            int lp = lp0 + j * 16 + c;
            #pragma unroll
            for (int r = 0; r < 4; r++) {
                int co = wco + i * 16 + g * 4 + r;
                yds[((size_t)n * CO + co) * LD + lp] = acc[i][j][r];
            }
        }
}

// ------------- BN stats reduce -------------
__global__ void bnstats(const float* __restrict__ ps, const float* __restrict__ pq,
                        const float* __restrict__ dg, const float* __restrict__ db,
                        float* __restrict__ scale, float* __restrict__ shift) {
    int co = blockIdx.x;
    int tid = threadIdx.x;
    float s = 0.f, q = 0.f;
    #pragma unroll
    for (int it = 0; it < 8; it++) {
        s += ps[(size_t)co * 2048 + it * 256 + tid];
        q += pq[(size_t)co * 2048 + it * 256 + tid];
    }
    #pragma unroll
    for (int m = 1; m < 64; m <<= 1) { s += __shfl_xor(s, m); q += __shfl_xor(q, m); }
    __shared__ float a[4], b[4];
    if ((tid & 63) == 0) { a[tid >> 6] = s; b[tid >> 6] = q; }
    __syncthreads();
    if (tid == 0) {
        s = a[0] + a[1] + a[2] + a[3];
        q = b[0] + b[1] + b[2] + b[3];
        const float inv = 1.f / ((float)NN * (float)LD);
        float mean = s * inv;
        float var = q * inv - mean * mean;
        float rstd = rsqrtf(var + 1e-5f);
        float sc = dg[co] * rstd;
        scale[co] = sc;
        shift[co] = db[co] - mean * sc;
    }
}

// ------------- BN + mish apply -------------
__global__ void bn_apply(const float* __restrict__ yds, const float* __restrict__ scale,
                         const float* __restrict__ shift, float* __restrict__ out) {
    size_t idx = (size_t)blockIdx.x * 256 + threadIdx.x;
    int row = (int)(idx >> 10);
    int co = row & (CO - 1);
    float sc = scale[co], sf = shift[co];
    f32x4 v = *(const f32x4*)&yds[idx * 4];
    #pragma unroll
    for (int e = 0; e < 4; e++) v[e] = mishf(fmaf(v[e], sc, sf));
    *(f32x4*)&out[idx * 4] = v;
}

extern "C" void kernel_launch(void* const* d_in, const int* in_sizes, int n_in,
                              void* d_out, int out_size, void* d_ws, size_t ws_size,
                              hipStream_t stream) {
    const float* x     = (const float*)d_in[0];
    const float* t     = (const float*)d_in[1];
    const float* l1_k5 = (const float*)d_in[2];
    const float* l1_k3 = (const float*)d_in[3];
    const float* l1_k1 = (const float*)d_in[4];
    const float* l1_a3 = (const float*)d_in[5];
    const float* l1_a5 = (const float*)d_in[6];
    const float* l1_gw = (const float*)d_in[7];
    const float* l1_gb = (const float*)d_in[8];
    const float* l1_ga = (const float*)d_in[9];
    const float* l1_be = (const float*)d_in[10];
    const float* l2_k5 = (const float*)d_in[11];
    const float* l2_k3 = (const float*)d_in[12];
    const float* l2_k1 = (const float*)d_in[13];
    const float* l2_a3 = (const float*)d_in[14];
    const float* l2_a5 = (const float*)d_in[15];
    const float* l2_gw = (const float*)d_in[16];
    const float* l2_gb = (const float*)d_in[17];
    const float* l2_ga = (const float*)d_in[18];
    const float* l2_be = (const float*)d_in[19];
    const float* dwp   = (const float*)d_in[20];
    const float* dg    = (const float*)d_in[21];
    const float* db    = (const float*)d_in[22];
    float* out = (float*)d_out;

    float* ws = (float*)d_ws;
    size_t o = 0;
    float* g1 = ws + o; o += 20480;
    float* g2 = ws + o; o += 20480;
    unsigned short* w1b = (unsigned short*)(ws + o); o += (size_t)NN * 2 * KK * CO * CI1 / 2;
    unsigned short* w2b = (unsigned short*)(ws + o); o += (size_t)NN * 2 * KK * CO * CO / 2;
    unsigned short* dwb = (unsigned short*)(ws + o); o += (size_t)4 * CO * CO / 2;
    float* ps = ws + o; o += 262144;
    float* pq = ws + o; o += 262144;
    float* scale1 = ws + o; o += 4096;
    float* shift1 = ws + o; o += 4096;
    float* scale2 = ws + o; o += 4096;
    float* shift2 = ws + o; o += 4096;
    float* scaled = ws + o; o += 128;
    float* shiftd = ws + o; o += 128;
    o = (o + 3) & ~(size_t)3;
    float* y = ws + o; o += (size_t)NN * LL * CO;
    unsigned short* hh = (unsigned short*)(ws + o); o += (size_t)NN * LL * CO / 2;
    unsigned short* hl = (unsigned short*)(ws + o); o += (size_t)NN * LL * CO / 2;

    const size_t XD_ELEMS = (size_t)NN * CO * LD;

    gates_kernel<<<(2 * NN * CO + 255) / 256, 256, 0, stream>>>(t, l1_gw, l1_gb, l2_gw, l2_gb, g1, g2);
    weights_prep<CI1><<<(NN * CI1 * CO + 255) / 256, 256, 0, stream>>>(g1, l1_k5, l1_k3, l1_k1, l1_a3, l1_a5, w1b);
    weights_prep<CO><<<(NN * CO * CO + 255) / 256, 256, 0, stream>>>(g2, l2_k5, l2_k3, l2_k1, l2_a3, l2_a5, w2b);
    dsw_prep<<<(CO * CO + 255) / 256, 256, 0, stream>>>(dwp, dwb);

    conv_mfma<CI1, true><<<dim3(LL / 128, 1, NN), 256, 0, stream>>>(x, nullptr, nullptr, w1b, y, ps, pq);
    stats_reduce<<<NN * CO, 64, 0, stream>>>(ps, pq, l1_ga, l1_be, scale1, shift1);
    napply<false><<<32768, 256, 0, stream>>>(y, scale1, shift1, hh, hl, nullptr);

    conv_mfma<CO, false><<<dim3(LL / 128, 1, NN), 256, 0, stream>>>(nullptr, hh, hl, w2b, y, ps, pq);
    stats_reduce<<<NN * CO, 64, 0, stream>>>(ps, pq, l2_ga, l2_be, scale2, shift2);
    napply<true><<<32768, 256, 0, stream>>>(y, scale2, shift2, nullptr, nullptr, out + XD_ELEMS);

    conv_ds_mfma<<<dim3(LD / 64, 1, NN), 256, 0, stream>>>(out + XD_ELEMS, dwb, y, ps, pq);
    bnstats<<<CO, 256, 0, stream>>>(ps, pq, dg, db, scaled, shiftd);
    bn_apply<<<(int)(XD_ELEMS / 4 / 256), 256, 0, stream>>>(y, scaled, shiftd, out);
}